// Round 5
// baseline (349.659 us; speedup 1.0000x reference)
//
#include <hip/hip_runtime.h>

// ---------------- workspace layout (floats) ----------------
#define N_P1    (512*16*50*32)          // 13,107,200
#define N_FEAT  (512*12800)             // 6,553,600
#define N_PART  (32*512*256)            // 4,194,304

#define WS_P1    0
#define WS_FEAT  (WS_P1 + N_P1)
#define WS_PART  (WS_FEAT + N_FEAT)
// after conv2 consumes P1, its region is reused:
#define WS_S1    0                       // 512*25*256 = 3,276,800  [b][t][k]

// ---------------- conv1: mean over T + conv3x3 + bn-fold + relu + pool ----------------
// grid (512, 5); 384 threads: one load item (352) / one compute item (320) per thread.
__global__ __launch_bounds__(384) void conv1_kernel(const float* __restrict__ x,
                                                    const float* __restrict__ w1,
                                                    const float* __restrict__ cb1,
                                                    const float* __restrict__ g1,
                                                    const float* __restrict__ bb1,
                                                    const float* __restrict__ m1g,
                                                    const float* __restrict__ v1,
                                                    float* __restrict__ p1) {
    __shared__ float xs[22 * 66];
    __shared__ float w1s[144];
    __shared__ float sh1s[16];
    const int b = blockIdx.x, s = blockIdx.y;
    const int tid = threadIdx.x;
    if (tid < 144) {
        int c = tid / 9;
        float inv = g1[c] * rsqrtf(v1[c] + 1e-5f);
        w1s[tid] = w1[tid] * inv;
    }
    if (tid >= 144 && tid < 160) {
        int c = tid - 144;
        float inv = g1[c] * rsqrtf(v1[c] + 1e-5f);
        sh1s[c] = cb1[c] * inv + bb1[c] - m1g[c] * inv;
    }
    if (tid >= 160 && tid < 204) {
        int q = tid - 160;
        xs[(q >> 1) * 66 + (q & 1) * 65] = 0.f;   // border cols
    }
    const int r0 = s * 20 - 1;
    const size_t TSTR = (size_t)512 * 6400;
    if (tid < 352) {
        int lr = tid >> 4, cq = tid & 15;
        int gr = r0 + lr;
        float4 a0 = make_float4(0.f, 0.f, 0.f, 0.f), a1 = a0, a2 = a0, a3 = a0;
        if (gr >= 0 && gr < 100) {
            const float* px = x + (size_t)b * 6400 + gr * 64 + cq * 4;
            #pragma unroll
            for (int tt = 0; tt < 24; tt += 4) {
                float4 v0 = *(const float4*)(px + (size_t)(tt + 0) * TSTR);
                float4 v1_ = *(const float4*)(px + (size_t)(tt + 1) * TSTR);
                float4 v2_ = *(const float4*)(px + (size_t)(tt + 2) * TSTR);
                float4 v3 = *(const float4*)(px + (size_t)(tt + 3) * TSTR);
                a0.x += v0.x; a0.y += v0.y; a0.z += v0.z; a0.w += v0.w;
                a1.x += v1_.x; a1.y += v1_.y; a1.z += v1_.z; a1.w += v1_.w;
                a2.x += v2_.x; a2.y += v2_.y; a2.z += v2_.z; a2.w += v2_.w;
                a3.x += v3.x; a3.y += v3.y; a3.z += v3.z; a3.w += v3.w;
            }
            float4 v = *(const float4*)(px + (size_t)24 * TSTR);
            a0.x += v.x; a0.y += v.y; a0.z += v.z; a0.w += v.w;
        }
        const float sc = 1.0f / 25.0f;
        float* d = &xs[lr * 66 + 1 + cq * 4];
        d[0] = (a0.x + a1.x + a2.x + a3.x) * sc;
        d[1] = (a0.y + a1.y + a2.y + a3.y) * sc;
        d[2] = (a0.z + a1.z + a2.z + a3.z) * sc;
        d[3] = (a0.w + a1.w + a2.w + a3.w) * sc;
    }
    __syncthreads();
    if (tid < 320) {
        int phl = tid >> 5, pw = tid & 31;
        int ph = s * 10 + phl;
        float win[4][4];
        #pragma unroll
        for (int a = 0; a < 4; ++a)
            #pragma unroll
            for (int c2 = 0; c2 < 4; ++c2)
                win[a][c2] = xs[(2 * phl + a) * 66 + 2 * pw + c2];
        #pragma unroll 1
        for (int c = 0; c < 16; ++c) {
            float s00 = 0.f, s01 = 0.f, s10 = 0.f, s11 = 0.f;
            #pragma unroll
            for (int dh = 0; dh < 3; ++dh)
                #pragma unroll
                for (int dw = 0; dw < 3; ++dw) {
                    float w = w1s[c * 9 + dh * 3 + dw];
                    s00 = fmaf(win[dh][dw],         w, s00);
                    s01 = fmaf(win[dh][dw + 1],     w, s01);
                    s10 = fmaf(win[dh + 1][dw],     w, s10);
                    s11 = fmaf(win[dh + 1][dw + 1], w, s11);
                }
            float m = fmaxf(fmaxf(s00, s01), fmaxf(s10, s11));
            float val = fmaxf(m + sh1s[c], 0.f);
            p1[(((size_t)b * 16 + c) * 50 + ph) * 32 + pw] = val;
        }
    }
}

// ---------------- conv2: conv3x3(16->32) + bn-fold + relu + pool, zero-waste ----------------
__global__ __launch_bounds__(320) void conv2_kernel(const float* __restrict__ p1,
                                                    const float* __restrict__ w2g,
                                                    const float* __restrict__ cb2,
                                                    const float* __restrict__ g2,
                                                    const float* __restrict__ bb2,
                                                    const float* __restrict__ m2g,
                                                    const float* __restrict__ v2,
                                                    float* __restrict__ feat) {
    __shared__ float ins[16 * 12 * 36];   // [ci][row -1..10][col -1..34]
    __shared__ float wl[16 * 9 * 32];     // [ci][tap][c]
    __shared__ float sh2s[32];
    const int b = blockIdx.x, s = blockIdx.y;
    const int tid = threadIdx.x;
    const int chg = tid & 15, q = (tid >> 4) & 3, phl = tid >> 6;
    const int ph = s * 5 + phl;

    for (int i = tid; i < 192; i += 320) {
        int ci = i / 12, lr = i - ci * 12;
        int gr = s * 10 - 1 + lr;
        float* dst = &ins[(ci * 12 + lr) * 36];
        if (gr >= 0 && gr < 50) {
            const float* src = p1 + (((size_t)b * 16 + ci) * 50 + gr) * 32;
            float4 v0 = *(const float4*)src;
            dst[0] = 0.f; dst[1] = v0.x; dst[2] = v0.y; dst[3] = v0.z;
            #pragma unroll
            for (int qq = 1; qq < 8; ++qq) {
                float4 v = *(const float4*)(src + 4 * qq - 1);
                *(float4*)(dst + 4 * qq) = v;
            }
            dst[32] = src[31];
            dst[33] = 0.f; dst[34] = 0.f; dst[35] = 0.f;
        } else {
            #pragma unroll
            for (int qq = 0; qq < 9; ++qq) *(float4*)(dst + 4 * qq) = make_float4(0.f, 0.f, 0.f, 0.f);
        }
    }
    for (int i = tid; i < 4608; i += 320) {
        int c = i / 144, rem = i - c * 144;
        float inv = g2[c] * rsqrtf(v2[c] + 1e-5f);
        wl[rem * 32 + c] = w2g[i] * inv;
    }
    if (tid < 32) {
        float inv = g2[tid] * rsqrtf(v2[tid] + 1e-5f);
        sh2s[tid] = cb2[tid] * inv + bb2[tid] - m2g[tid] * inv;
    }
    __syncthreads();

    float acc[2][2][8];
    #pragma unroll
    for (int c = 0; c < 2; ++c)
        #pragma unroll
        for (int a = 0; a < 2; ++a)
            #pragma unroll
            for (int xx = 0; xx < 8; ++xx) acc[c][a][xx] = 0.f;
    const int xb = q * 8;
    #pragma unroll 1
    for (int ci = 0; ci < 16; ++ci) {
        float2 wv[9];
        #pragma unroll
        for (int t = 0; t < 9; ++t)
            wv[t] = *(const float2*)&wl[(ci * 9 + t) * 32 + 2 * chg];
        #pragma unroll
        for (int lr4 = 0; lr4 < 4; ++lr4) {
            const float* row = &ins[(ci * 12 + (2 * phl + lr4)) * 36 + xb];
            float v[10];
            float4 t0 = *(const float4*)&row[0];
            float4 t1 = *(const float4*)&row[4];
            float2 t2 = *(const float2*)&row[8];
            v[0]=t0.x; v[1]=t0.y; v[2]=t0.z; v[3]=t0.w;
            v[4]=t1.x; v[5]=t1.y; v[6]=t1.z; v[7]=t1.w;
            v[8]=t2.x; v[9]=t2.y;
            #pragma unroll
            for (int a = 0; a < 2; ++a) {
                const int dh = lr4 - a;
                if (dh >= 0 && dh <= 2) {
                    #pragma unroll
                    for (int dw = 0; dw < 3; ++dw) {
                        float w0 = wv[dh * 3 + dw].x;
                        float w1 = wv[dh * 3 + dw].y;
                        #pragma unroll
                        for (int xx = 0; xx < 8; ++xx) {
                            acc[0][a][xx] = fmaf(v[xx + dw], w0, acc[0][a][xx]);
                            acc[1][a][xx] = fmaf(v[xx + dw], w1, acc[1][a][xx]);
                        }
                    }
                }
            }
        }
    }
    #pragma unroll
    for (int ch = 0; ch < 2; ++ch) {
        const int c = 2 * chg + ch;
        const float sh = sh2s[c];
        #pragma unroll
        for (int p = 0; p < 4; ++p) {
            float m = fmaxf(fmaxf(acc[ch][0][2 * p], acc[ch][0][2 * p + 1]),
                            fmaxf(acc[ch][1][2 * p], acc[ch][1][2 * p + 1]));
            float val = fmaxf(m + sh, 0.f);
            feat[(((size_t)b * 32 + c) * 25 + ph) * 16 + q * 4 + p] = val;
        }
    }
}

// ---------------- fc1: split-K f32 GEMM, 64x128 tile, 4x8 micro ----------------
__global__ __launch_bounds__(256) void fc1_kernel(const float* __restrict__ feat,
                                                  const float* __restrict__ w,
                                                  float* __restrict__ part) {
    __shared__ float As[16 * 68];
    __shared__ float Bs[16 * 136];
    const int bx = blockIdx.x, by = blockIdx.y, bz = blockIdx.z;
    const int tid = threadIdx.x;
    const int tm = tid >> 4, tn = tid & 15;
    const int r = tid >> 2, cq = tid & 3;
    const int m0 = bx * 64, n0 = by * 128;
    const size_t aBase = (size_t)(m0 + r) * 12800 + bz * 400 + cq * 4;
    const size_t bBase = (size_t)(n0 + r) * 12800 + bz * 400 + cq * 4;
    float acc[4][8];
    #pragma unroll
    for (int i = 0; i < 4; ++i)
        #pragma unroll
        for (int j = 0; j < 8; ++j) acc[i][j] = 0.f;

    for (int kt = 0; kt < 25; ++kt) {
        float4 a0 = *(const float4*)(feat + aBase + kt * 16);
        float4 b0 = *(const float4*)(w    + bBase + kt * 16);
        float4 b1 = *(const float4*)(w    + bBase + (size_t)64 * 12800 + kt * 16);
        __syncthreads();
        As[(cq * 4 + 0) * 68 + r] = a0.x; As[(cq * 4 + 1) * 68 + r] = a0.y;
        As[(cq * 4 + 2) * 68 + r] = a0.z; As[(cq * 4 + 3) * 68 + r] = a0.w;
        Bs[(cq * 4 + 0) * 136 + r]      = b0.x; Bs[(cq * 4 + 1) * 136 + r]      = b0.y;
        Bs[(cq * 4 + 2) * 136 + r]      = b0.z; Bs[(cq * 4 + 3) * 136 + r]      = b0.w;
        Bs[(cq * 4 + 0) * 136 + 64 + r] = b1.x; Bs[(cq * 4 + 1) * 136 + 64 + r] = b1.y;
        Bs[(cq * 4 + 2) * 136 + 64 + r] = b1.z; Bs[(cq * 4 + 3) * 136 + 64 + r] = b1.w;
        __syncthreads();
        #pragma unroll
        for (int kk = 0; kk < 16; ++kk) {
            float4 av  = *(const float4*)&As[kk * 68 + tm * 4];
            float4 bv0 = *(const float4*)&Bs[kk * 136 + tn * 8];
            float4 bv1 = *(const float4*)&Bs[kk * 136 + tn * 8 + 4];
            float a_[4] = {av.x, av.y, av.z, av.w};
            float b_[8] = {bv0.x, bv0.y, bv0.z, bv0.w, bv1.x, bv1.y, bv1.z, bv1.w};
            #pragma unroll
            for (int i = 0; i < 4; ++i)
                #pragma unroll
                for (int j = 0; j < 8; ++j)
                    acc[i][j] = fmaf(a_[i], b_[j], acc[i][j]);
        }
    }
    #pragma unroll
    for (int i = 0; i < 4; ++i) {
        float* dst = &part[(size_t)bz * 131072 + (size_t)(m0 + tm * 4 + i) * 256 + n0 + tn * 8];
        *(float4*)dst       = make_float4(acc[i][0], acc[i][1], acc[i][2], acc[i][3]);
        *(float4*)(dst + 4) = make_float4(acc[i][4], acc[i][5], acc[i][6], acc[i][7]);
    }
}

// ---------------- lif1: reduce fc1 partials + 25-step m1 scan -> S1 [b][t][k] ----------------
__global__ __launch_bounds__(256) void lif1_kernel(const float* __restrict__ part,
                                                   const float* __restrict__ b1g,
                                                   const float* __restrict__ pb1,
                                                   float* __restrict__ S1) {
    const int i = blockIdx.x * 256 + threadIdx.x;    // 131072 = 512 b x 256 k
    const int k = i & 255;
    const int b = i >> 8;
    float cu = b1g[k];
    #pragma unroll 8
    for (int z = 0; z < 32; ++z) cu += part[(size_t)z * 131072 + i];
    const float be = fminf(fmaxf(pb1[0], 0.f), 1.f);
    float m = 0.f;
    float* dst = S1 + (size_t)b * 6400 + k;
    #pragma unroll
    for (int t = 0; t < 25; ++t) {
        float r = (m > 1.f) ? 1.f : 0.f;
        m = fmaf(be, m, cu) - r;
        dst[t * 256] = (m > 1.f) ? 1.f : 0.f;
    }
}

// ---------------- tail: fc2 GEMM + lif2 + fc3 + lif3, one block per batch row ----------------
// 512 blocks x 320 threads. S1 row-slab (25x256) in LDS; w2 streamed in 32-k chunks.
__global__ __launch_bounds__(320) void tail_kernel(const float* __restrict__ S1,
                                                   const float* __restrict__ w2g,
                                                   const float* __restrict__ b2g,
                                                   const float* __restrict__ w3g,
                                                   const float* __restrict__ b3g,
                                                   const float* __restrict__ pb2,
                                                   const float* __restrict__ pb3,
                                                   float* __restrict__ out) {
    __shared__ float s1L[25 * 256];    // [t][k]
    __shared__ float w2T[32 * 133];    // [kk][j], pad 133 (conflict-free)
    __shared__ float w3T[128 * 36];    // [k][c]
    __shared__ float in2L[25 * 128];   // [t][j]; spikes written in-place
    __shared__ float a3L[25 * 36];     // [t][c]
    const int b = blockIdx.x;
    const int tid = threadIdx.x;
    const int tm = tid >> 6;           // 0..4  (5 t-rows each)
    const int tn = tid & 63;           // j = 2*tn, 2*tn+1

    // stage S1 slab (contiguous 6400 floats)
    for (int i = tid; i < 1600; i += 320)
        *(float4*)&s1L[i * 4] = *(const float4*)&S1[(size_t)b * 6400 + i * 4];
    // w3 transpose: w3T[k][c] = w3g[c*128+k]
    for (int i = tid; i < 4480; i += 320) {
        int c = i >> 7, k = i & 127;
        w3T[k * 36 + c] = w3g[i];
    }

    float acc[5][2];
    #pragma unroll
    for (int i = 0; i < 5; ++i) { acc[i][0] = 0.f; acc[i][1] = 0.f; }

    #pragma unroll 1
    for (int kt = 0; kt < 8; ++kt) {           // 8 chunks of 32 k
        __syncthreads();
        for (int i = tid; i < 4096; i += 320) {
            int j = i >> 5, kk = i & 31;
            w2T[kk * 133 + j] = w2g[j * 256 + kt * 32 + kk];
        }
        __syncthreads();
        #pragma unroll
        for (int kk = 0; kk < 32; ++kk) {
            float2 wv = *(const float2*)&w2T[kk * 133 + 2 * tn];
            const float* ap = &s1L[tm * 5 * 256 + kt * 32 + kk];
            #pragma unroll
            for (int i = 0; i < 5; ++i) {
                float a = ap[i * 256];
                acc[i][0] = fmaf(a, wv.x, acc[i][0]);
                acc[i][1] = fmaf(a, wv.y, acc[i][1]);
            }
        }
    }
    {
        float2 bias = *(const float2*)&b2g[2 * tn];
        #pragma unroll
        for (int i = 0; i < 5; ++i) {
            int t = tm * 5 + i;
            *(float2*)&in2L[t * 128 + 2 * tn] = make_float2(acc[i][0] + bias.x,
                                                            acc[i][1] + bias.y);
        }
    }
    __syncthreads();
    // lif2 scan, spikes in-place (threads 0..127)
    if (tid < 128) {
        const float be2 = fminf(fmaxf(pb2[0], 0.f), 1.f);
        float m = 0.f;
        #pragma unroll
        for (int t = 0; t < 25; ++t) {
            float r = (m > 1.f) ? 1.f : 0.f;
            m = fmaf(be2, m, in2L[t * 128 + tid]) - r;
            in2L[t * 128 + tid] = (m > 1.f) ? 1.f : 0.f;
        }
    }
    __syncthreads();
    // fc3 dots: 875 = 25 t x 35 c
    for (int i = tid; i < 875; i += 320) {
        int t = i / 35, c = i - t * 35;
        float a = b3g[c];
        const float* sp = &in2L[t * 128];
        const float* wp = &w3T[c];
        #pragma unroll 8
        for (int k = 0; k < 128; ++k)
            a = fmaf(sp[k], wp[k * 36], a);
        a3L[t * 36 + c] = a;
    }
    __syncthreads();
    // lif3 scan + output (threads 0..34)
    if (tid < 35) {
        const float be3 = fminf(fmaxf(pb3[0], 0.f), 1.f);
        float m = 0.f;
        #pragma unroll
        for (int t = 0; t < 25; ++t) {
            float r = (m > 1.f) ? 1.f : 0.f;
            m = fmaf(be3, m, a3L[t * 36 + tid]) - r;
            out[((size_t)t * 512 + b) * 35 + tid] = (m > 1.f) ? 1.f : 0.f;
        }
    }
}

// ---------------- launch ----------------
extern "C" void kernel_launch(void* const* d_in, const int* in_sizes, int n_in,
                              void* d_out, int out_size, void* d_ws, size_t ws_size,
                              hipStream_t stream) {
    const float* x     = (const float*)d_in[0];
    const float* c1w   = (const float*)d_in[1];
    const float* c1b   = (const float*)d_in[2];
    const float* bn1g  = (const float*)d_in[3];
    const float* bn1b  = (const float*)d_in[4];
    const float* bn1m  = (const float*)d_in[5];
    const float* bn1v  = (const float*)d_in[6];
    const float* c2w   = (const float*)d_in[7];
    const float* c2b   = (const float*)d_in[8];
    const float* bn2g  = (const float*)d_in[9];
    const float* bn2b  = (const float*)d_in[10];
    const float* bn2m  = (const float*)d_in[11];
    const float* bn2v  = (const float*)d_in[12];
    const float* fc1w  = (const float*)d_in[13];
    const float* fc1b  = (const float*)d_in[14];
    const float* fc2w  = (const float*)d_in[15];
    const float* fc2b  = (const float*)d_in[16];
    const float* fc3w  = (const float*)d_in[17];
    const float* fc3b  = (const float*)d_in[18];
    const float* beta1 = (const float*)d_in[19];
    const float* beta2 = (const float*)d_in[20];
    const float* beta3 = (const float*)d_in[21];
    float* ws  = (float*)d_ws;
    float* out = (float*)d_out;

    conv1_kernel<<<dim3(512, 5), 384, 0, stream>>>(x, c1w, c1b, bn1g, bn1b, bn1m, bn1v,
                                                   ws + WS_P1);
    conv2_kernel<<<dim3(512, 5), 320, 0, stream>>>(ws + WS_P1, c2w, c2b, bn2g, bn2b, bn2m, bn2v,
                                                   ws + WS_FEAT);
    fc1_kernel<<<dim3(8, 2, 32), 256, 0, stream>>>(ws + WS_FEAT, fc1w, ws + WS_PART);
    lif1_kernel<<<512, 256, 0, stream>>>(ws + WS_PART, fc1b, beta1, ws + WS_S1);
    tail_kernel<<<512, 320, 0, stream>>>(ws + WS_S1, fc2w, fc2b, fc3w, fc3b,
                                         beta2, beta3, out);
}